// Round 13
// baseline (1602.586 us; speedup 1.0000x reference)
//
#include <hip/hip_runtime.h>
#include <hip/hip_bf16.h>

typedef _Float16 f16;
typedef __attribute__((ext_vector_type(8))) _Float16 f16x8;
typedef __attribute__((ext_vector_type(2))) _Float16 f16x2;
typedef __attribute__((ext_vector_type(4))) float f32x4;

constexpr int CB = 64, CP = 196, CH = 512, CV = 30000, CVP = 30080, CT = 20;
constexpr int NT = 235;  // preds col tiles

__device__ __forceinline__ float sigf(float x) { return 1.f / (1.f + __expf(-x)); }

#if defined(__has_builtin)
#if __has_builtin(__builtin_amdgcn_fdot2)
#define HAVE_FDOT2 1
#endif
#endif

__device__ __forceinline__ f16x2 asf16x2(unsigned u) {
    union { unsigned x; f16x2 h; } c; c.x = u; return c.h;
}
__device__ __forceinline__ float dotp(f16x2 a, f16x2 b, float c) {
#ifdef HAVE_FDOT2
    return __builtin_amdgcn_fdot2(a, b, c, false);
#else
    return fmaf((float)a[0], (float)b[0], fmaf((float)a[1], (float)b[1], c));
#endif
}

// ---- relaxed agent-scope (sc1, L3-coherent) helpers
__device__ __forceinline__ unsigned ald_u(const unsigned* p) {
    return __hip_atomic_load(p, __ATOMIC_RELAXED, __HIP_MEMORY_SCOPE_AGENT);
}
__device__ __forceinline__ void ast_u(unsigned* p, unsigned v) {
    __hip_atomic_store(p, v, __ATOMIC_RELAXED, __HIP_MEMORY_SCOPE_AGENT);
}
__device__ __forceinline__ float ald_f(const float* p) {
    return __hip_atomic_load(p, __ATOMIC_RELAXED, __HIP_MEMORY_SCOPE_AGENT);
}
__device__ __forceinline__ void ast_f(float* p, float v) {
    __hip_atomic_store(p, v, __ATOMIC_RELAXED, __HIP_MEMORY_SCOPE_AGENT);
}

// ---- 16-producer slot sync (one 64B line per sync point per quad).
__device__ __forceinline__ void wait16(const int* base, int target) {
    if (threadIdx.x < 64) {
        for (;;) {
            int v = __hip_atomic_load(base + (threadIdx.x & 15), __ATOMIC_RELAXED,
                                      __HIP_MEMORY_SCOPE_AGENT);
            if (__all(v >= target)) break;
            __builtin_amdgcn_s_sleep(1);
        }
    }
    __builtin_amdgcn_s_barrier();   // raw barrier: does NOT drain vmcnt
    __builtin_amdgcn_sched_barrier(0);
}
__device__ __forceinline__ void post16(int* slot, int val) {
    __syncthreads();
    if (threadIdx.x == 0)
        __hip_atomic_store(slot, val, __ATOMIC_RELAXED, __HIP_MEMORY_SCOPE_AGENT);
}

// ---------------------------------------------------------------------------
// mega convert/transpose/prep kernel (one-time prologue)
//   W1L[s(16)][kk4(64)][o(64)][8] : global out O=64s+o; O<512 -> att2 dim O
//   BpL[s(16)][kk4(128)][o(128)][8]: c = 128s+o (c=4d+g); K=[xawe;h]
//   WihE_p[c][512]                 : c = 4d+g rows of W_ih cols 0..511
// ---------------------------------------------------------------------------
__device__ __forceinline__ void cvt8(const float* __restrict__ s, f16* __restrict__ d) {
    float4 a = *(const float4*)s;
    float4 b = *(const float4*)(s + 4);
    f16x8 o;
    o[0] = (f16)a.x; o[1] = (f16)a.y; o[2] = (f16)a.z; o[3] = (f16)a.w;
    o[4] = (f16)b.x; o[5] = (f16)b.y; o[6] = (f16)b.z; o[7] = (f16)b.w;
    *(f16x8*)d = o;
}

__global__ __launch_bounds__(256) void k_mega(
    const float* __restrict__ enc, const float* __restrict__ W_ea,
    const float* __restrict__ W_da, const float* __restrict__ W_fb,
    const float* __restrict__ W_ih, const float* __restrict__ W_hh,
    const float* __restrict__ W_fc, const float* __restrict__ emb,
    const int* __restrict__ caps, const float* __restrict__ b_da,
    const float* __restrict__ b_fb, const float* __restrict__ b_ih,
    const float* __restrict__ b_hh,
    f16* __restrict__ enc_h, f16* __restrict__ Wea_h, f16* __restrict__ W1L,
    f16* __restrict__ BpL, f16* __restrict__ WihE_p, f16* __restrict__ Wfc_h,
    f16* __restrict__ embg, float* __restrict__ bcat, float* __restrict__ bsum_p,
    int* __restrict__ gsync)
{
    constexpr long long E0 = 802816;            // enc cvt
    constexpr long long E1 = E0 + 32768;        // W_ea
    constexpr long long E2 = E1 + 1920000;      // W_fc
    constexpr long long E3 = E2 + 5120;         // Wfc pad zeros
    constexpr long long E4 = E3 + 81920;        // emb gather
    constexpr long long E5 = E4 + 65536;        // W1L  (16s x 64kk4 x 64o)
    constexpr long long E6 = E5 + 262144;       // BpL  (16s x 128kk4 x 128o)
    constexpr long long E7 = E6 + 131072;       // WihE_p (2048c x 64)
    constexpr long long E8 = E7 + 3072;         // biases
    constexpr long long TOT = E8 + 1024;        // gsync zero

    for (long long id = (long long)blockIdx.x * 256 + threadIdx.x; id < TOT;
         id += (long long)gridDim.x * 256) {
        if (id < E0) {
            cvt8(enc + id * 8, enc_h + id * 8);
        } else if (id < E1) {
            long long c = id - E0; cvt8(W_ea + c * 8, Wea_h + c * 8);
        } else if (id < E2) {
            long long c = id - E1; cvt8(W_fc + c * 8, Wfc_h + c * 8);
        } else if (id < E3) {
            long long c = id - E2; f16x8 z = {};
            *(f16x8*)&Wfc_h[15360000 + c * 8] = z;
        } else if (id < E4) {
            long long c = id - E3; int m = (int)(c >> 6), j = (int)(c & 63);
            int tt = m >> 6, bb = m & 63;
            int row = caps[bb * 21 + tt];
            cvt8(emb + (size_t)row * 512 + j * 8, embg + (size_t)m * 512 + j * 8);
        } else if (id < E5) {
            long long c = id - E4;
            int o = (int)(c & 63), kk4 = (int)((c >> 6) & 63), s = (int)(c >> 12);
            int O = 64 * s + o;
            const float* src = (O < 512) ? &W_da[(size_t)O * 512]
                                         : &W_fb[(size_t)(O - 512) * 512];
            cvt8(src + kk4 * 8, &W1L[(((size_t)s * 64 + kk4) * 64 + o) * 8]);
        } else if (id < E6) {
            long long c = id - E5;
            int o = (int)(c & 127), kk4 = (int)((c >> 7) & 127), s = (int)(c >> 14);
            int d = 32 * s + (o >> 2), g = o & 3;
            int r = g * 512 + d;
            const float* src = (kk4 < 64) ? &W_ih[(size_t)r * 1024 + 512 + kk4 * 8]
                                          : &W_hh[(size_t)r * 512 + (kk4 - 64) * 8];
            cvt8(src, &BpL[(((size_t)s * 128 + kk4) * 128 + o) * 8]);
        } else if (id < E7) {
            long long c = id - E6;
            int cc = (int)(c >> 6), j8 = (int)(c & 63);
            int r = (cc & 3) * 512 + (cc >> 2);
            cvt8(W_ih + (size_t)r * 1024 + j8 * 8, WihE_p + (size_t)cc * 512 + j8 * 8);
        } else if (id < E8) {
            int i = (int)(id - E7);
            if (i < 512) bcat[i] = b_da[i];
            else if (i < 1024) bcat[i] = b_fb[i - 512];
            else {
                int cc = i - 1024;
                int r = (cc & 3) * 512 + (cc >> 2);
                bsum_p[cc] = b_ih[r] + b_hh[r];
            }
        } else {
            gsync[(int)(id - E8)] = 0;
        }
    }
}

// h0 = mean_p(enc) -> hbuf slot 0 (f16) and cinit (f32)
__global__ __launch_bounds__(256) void k_h0(const float* __restrict__ enc,
                                            f16* __restrict__ hbuf, float* __restrict__ cinit)
{
    int b = blockIdx.x;
    for (int h = threadIdx.x; h < CH; h += 256) {
        const float* p = enc + (size_t)b * CP * CH + h;
        float s = 0.f;
        for (int q = 0; q < CP; ++q) s += p[q * CH];
        s *= (1.f / 196.f);
        hbuf[b * CH + h] = (f16)s;
        cinit[b * CH + h] = s;
    }
}

// ---------------------------------------------------------------------------
// K=512 GEMM: tile 128x128, BK=32, padded LDS, reg prefetch.
// EPI_PREDS: 1-D grid 2400 with XCD-pinning swizzle (B tile L2-resident).
// ---------------------------------------------------------------------------
enum { EPI_F16B = 0, EPI_F32B = 1, EPI_PREDS = 2 };

template <int EPI>
__global__ __launch_bounds__(256) void gemm_k512(
    const f16* __restrict__ Aptr, const f16* __restrict__ Bptr, int N,
    const float* __restrict__ bias, float* __restrict__ Cf,
    f16* __restrict__ Ch, const int* __restrict__ lengths)
{
    constexpr int LD = 40;
    const int tid = threadIdx.x;
    const int lane = tid & 63, wave = tid >> 6;
    const int wr = wave >> 1, wc = wave & 1;
    int bx, by;
    if constexpr (EPI == EPI_PREDS) {
        int bid1 = blockIdx.x;
        int nt = (bid1 / 80) * 8 + (bid1 & 7);
        int mt = (bid1 >> 3) % 10;
        if (nt >= NT) return;
        bx = nt; by = mt;
    } else {
        bx = blockIdx.x; by = blockIdx.y;
    }

    __shared__ f16 As[128 * LD];
    __shared__ f16 Bs[128 * LD];

    const f16* Ag = Aptr + (size_t)by * 128 * 512;
    const f16* Bg = Bptr + (size_t)bx * 128 * 512;

    int srow[2], skc[2];
#pragma unroll
    for (int i = 0; i < 2; ++i) { int ci = tid + i * 256; srow[i] = ci >> 2; skc[i] = (ci & 3) * 8; }

    f32x4 acc[4][4] = {};
    f16x8 ar[2], br[2];
#pragma unroll
    for (int i = 0; i < 2; ++i) {
        ar[i] = *(const f16x8*)&Ag[(size_t)srow[i] * 512 + skc[i]];
        br[i] = *(const f16x8*)&Bg[(size_t)srow[i] * 512 + skc[i]];
    }

    const int rr = lane & 15, kg = (lane >> 4) * 8;
    for (int kt = 0; kt < 16; ++kt) {
        __syncthreads();
#pragma unroll
        for (int i = 0; i < 2; ++i) {
            *(f16x8*)&As[srow[i] * LD + skc[i]] = ar[i];
            *(f16x8*)&Bs[srow[i] * LD + skc[i]] = br[i];
        }
        __syncthreads();
        if (kt < 15) {
            int k0 = (kt + 1) * 32;
#pragma unroll
            for (int i = 0; i < 2; ++i) {
                ar[i] = *(const f16x8*)&Ag[(size_t)srow[i] * 512 + k0 + skc[i]];
                br[i] = *(const f16x8*)&Bg[(size_t)srow[i] * 512 + k0 + skc[i]];
            }
        }
        f16x8 af[4], bf[4];
#pragma unroll
        for (int mi = 0; mi < 4; ++mi) af[mi] = *(const f16x8*)&As[(wr * 64 + mi * 16 + rr) * LD + kg];
#pragma unroll
        for (int ni = 0; ni < 4; ++ni) bf[ni] = *(const f16x8*)&Bs[(wc * 64 + ni * 16 + rr) * LD + kg];
#pragma unroll
        for (int mi = 0; mi < 4; ++mi)
#pragma unroll
            for (int ni = 0; ni < 4; ++ni)
                acc[mi][ni] = __builtin_amdgcn_mfma_f32_16x16x32_f16(af[mi], bf[ni], acc[mi][ni], 0, 0, 0);
    }

    const int m0 = by * 128 + wr * 64;
    const int n0 = bx * 128 + wc * 64;
    const int r0 = (lane >> 4) * 4, cc = lane & 15;
#pragma unroll
    for (int mi = 0; mi < 4; ++mi) {
#pragma unroll
        for (int ni = 0; ni < 4; ++ni) {
#pragma unroll
            for (int r = 0; r < 4; ++r) {
                int m = m0 + mi * 16 + r0 + r;
                int n = n0 + ni * 16 + cc;
                float v = acc[mi][ni][r];
                if constexpr (EPI == EPI_F16B) {
                    Ch[(size_t)m * N + n] = (f16)(v + bias[n]);
                } else if constexpr (EPI == EPI_F32B) {
                    Cf[(size_t)m * N + n] = v + bias[n];
                } else {
                    if (n < CV) {
                        int tt = m >> 6, b = m & 63;
                        float val = ((lengths[b] - 1) > tt) ? (v + bias[n]) : 0.f;
                        __builtin_nontemporal_store(val, &Cf[(size_t)b * (CT * CV) + (size_t)tt * CV + n]);
                    }
                }
            }
        }
    }
}

// ---------------------------------------------------------------------------
// Recurrence: 256 blocks = 16 quads (4 batches) x 16 out-slices, 512 threads.
// 3 sync points/step: s1 (att2), s3 (xawe), s4 (h).
// e is computed redundantly (all 196 rows per block) -> softmax fully local.
// Phase-1 weights + 12/32 of phase-4 weights live in registers permanently;
// 12 more phase-4 chunks prefetched between post(s3) and wait(s3).
// ---------------------------------------------------------------------------
__global__ __launch_bounds__(512) void k_loopQ(
    const f16* __restrict__ att1, const f16* __restrict__ ench,
    const f16* __restrict__ W1L, const f16* __restrict__ BpL,
    const float* __restrict__ embIH, const float* __restrict__ Wfa,
    const float* __restrict__ bfa, const float* __restrict__ bcat,
    const int* __restrict__ lens, const float* __restrict__ cinit,
    f16* __restrict__ hbuf, float* __restrict__ alph,
    float* __restrict__ xatt2, float* __restrict__ xxa, int* __restrict__ gsync)
{
    const int bid = blockIdx.x, tid = threadIdx.x;
    const int lane = tid & 63, wv = tid >> 6;
    const int q4 = bid >> 4, s = bid & 15;
    const int b0 = 4 * q4;
    const int batt = b0 + (s & 3), q = s >> 2;

    int* sl = gsync + q4 * 64;  // [s1|s3|s4] x 16

    __shared__ __align__(16) f16 h_s[4 * 512];
    __shared__ __align__(16) float part[2048];
    __shared__ float a2f[512], ga_s[128];
    __shared__ float es[200], als[200], red[16];
    __shared__ float awp[32][128];
    __shared__ __align__(16) f16 xh_s[4 * 1024];
    __shared__ float gt[512];
    __shared__ f16 htmp[128];
    __shared__ float c_s[128];

    ((unsigned*)h_s)[tid] = ((const unsigned*)(hbuf + b0 * 512))[tid];
    ((unsigned*)h_s)[tid + 512] = ((const unsigned*)(hbuf + b0 * 512))[tid + 512];
    if (tid < 128) c_s[tid] = cinit[(b0 + (tid >> 5)) * 512 + 32 * s + (tid & 31)];

    const float bfa0 = bfa[0];
    const int lb = lens[batt];
    float wfr[8];
#pragma unroll
    for (int j = 0; j < 8; ++j) wfr[j] = Wfa[lane * 8 + j];
    const int ar_ = lane >> 4, ac_ = lane & 15;
    const int ks1 = tid >> 6, o1 = tid & 63;     // phase1: K-split 8 x 64 outs
    const int ks4 = tid >> 7, o4 = tid & 127;    // phase4: K-split 4 x 128 outs

    // -------- persistent register-resident weights --------
    const f16* wp1 = W1L + (((size_t)s * 64 + ks1 * 8) * 64 + o1) * 8;
    uint4 w1h[8];
#pragma unroll
    for (int i = 0; i < 8; ++i) w1h[i] = *(const uint4*)(wp1 + (size_t)i * 512);

    const f16* wp4 = BpL + (((size_t)s * 128 + ks4 * 32) * 128 + o4) * 8;
    uint4 w4h[12];
#pragma unroll
    for (int i = 0; i < 12; ++i) w4h[i] = *(const uint4*)(wp4 + (size_t)i * 1024);

    __syncthreads();

    for (int t = 0; t < CT; ++t) {
        if (t > 0) {
            wait16(sl + 32, t);
            const unsigned* hp = (const unsigned*)(hbuf + (size_t)t * 32768 + b0 * 512);
            ((unsigned*)h_s)[tid] = ald_u(hp + tid);
            ((unsigned*)h_s)[tid + 512] = ald_u(hp + tid + 512);
            __syncthreads();
        }

        // ---- phase 1: att2+gate outs [64s,64s+64) x 4 batches (K-split 8) ----
        {
            const uint4* xq = (const uint4*)h_s;
            float a0 = 0.f, a1 = 0.f, a2 = 0.f, a3 = 0.f;
#pragma unroll
            for (int i = 0; i < 8; ++i) {
                uint4 w = w1h[i];
                int kk4 = ks1 * 8 + i;
                uint4 x0 = xq[kk4], x1 = xq[64 + kk4], x2 = xq[128 + kk4], x3 = xq[192 + kk4];
                a0 = dotp(asf16x2(w.x), asf16x2(x0.x), a0);
                a1 = dotp(asf16x2(w.x), asf16x2(x1.x), a1);
                a2 = dotp(asf16x2(w.x), asf16x2(x2.x), a2);
                a3 = dotp(asf16x2(w.x), asf16x2(x3.x), a3);
                a0 = dotp(asf16x2(w.y), asf16x2(x0.y), a0);
                a1 = dotp(asf16x2(w.y), asf16x2(x1.y), a1);
                a2 = dotp(asf16x2(w.y), asf16x2(x2.y), a2);
                a3 = dotp(asf16x2(w.y), asf16x2(x3.y), a3);
                a0 = dotp(asf16x2(w.z), asf16x2(x0.z), a0);
                a1 = dotp(asf16x2(w.z), asf16x2(x1.z), a1);
                a2 = dotp(asf16x2(w.z), asf16x2(x2.z), a2);
                a3 = dotp(asf16x2(w.z), asf16x2(x3.z), a3);
                a0 = dotp(asf16x2(w.w), asf16x2(x0.w), a0);
                a1 = dotp(asf16x2(w.w), asf16x2(x1.w), a1);
                a2 = dotp(asf16x2(w.w), asf16x2(x2.w), a2);
                a3 = dotp(asf16x2(w.w), asf16x2(x3.w), a3);
            }
            f32x4 pk; pk[0] = a0; pk[1] = a1; pk[2] = a2; pk[3] = a3;
            *(f32x4*)&part[ks1 * 256 + o1 * 4] = pk;
        }
        __syncthreads();
        if (tid < 256) {
            float v = 0.f;
#pragma unroll
            for (int w8 = 0; w8 < 8; ++w8) v += part[w8 * 256 + tid];
            int o = tid >> 2, bb = tid & 3;
            int O = 64 * s + o;
            ast_f(&xatt2[(size_t)(b0 + bb) * 1024 + O], v + bcat[O]);
        }
        post16(sl + s, t + 1);

        // prefetch first 8 att1 rows (p = wv + 8i < 64+wv) -- overlaps s1 poll
        f16x8 fr[8];
#pragma unroll
        for (int i = 0; i < 8; ++i)
            fr[i] = *(const f16x8*)&att1[((size_t)batt * CP + wv + 8 * i) * 512 + lane * 8];

        wait16(sl, t + 1);
        a2f[tid] = ald_f(&xatt2[(size_t)batt * 1024 + tid]);
        if (tid < 128) ga_s[tid] = ald_f(&xatt2[(size_t)batt * 1024 + 512 + 128 * q + tid]);
        __syncthreads();

        // ---- phase 2 (local): e for ALL 196 rows of batt ----
        {
            float a2r[8];
#pragma unroll
            for (int j = 0; j < 8; ++j) a2r[j] = a2f[lane * 8 + j];
#pragma unroll
            for (int i = 0; i < 8; ++i) {
                float e = 0.f;
#pragma unroll
                for (int j = 0; j < 8; ++j)
                    e += fmaxf((float)fr[i][j] + a2r[j], 0.f) * wfr[j];
#pragma unroll
                for (int o = 32; o; o >>= 1) e += __shfl_down(e, o);
                if (lane == 0) es[wv + 8 * i] = e + bfa0;
            }
#pragma unroll 4
            for (int i = 8; i < 25; ++i) {
                int p = wv + 8 * i;
                if (p < CP) {
                    f16x8 av = *(const f16x8*)&att1[((size_t)batt * CP + p) * 512 + lane * 8];
                    float e = 0.f;
#pragma unroll
                    for (int j = 0; j < 8; ++j)
                        e += fmaxf((float)av[j] + a2r[j], 0.f) * wfr[j];
#pragma unroll
                    for (int o = 32; o; o >>= 1) e += __shfl_down(e, o);
                    if (lane == 0) es[p] = e + bfa0;
                }
            }
        }

        // prefetch enc awe fragments (lands during softmax)
        f16x8 er[7];
#pragma unroll
        for (int it = 0; it < 7; ++it) {
            int p = it * 32 + wv * 4 + ar_;
            if (p < CP)
                er[it] = *(const f16x8*)&ench[((size_t)batt * CP + p) * 512 + 128 * q + ac_ * 8];
        }
        __syncthreads();

        // ---- phase 3: softmax (local) + awe h-slice + xawe ----
        {
            float ev = (tid < CP) ? es[tid] : -1e30f;
            float mx = ev;
#pragma unroll
            for (int o = 32; o; o >>= 1) mx = fmaxf(mx, __shfl_down(mx, o));
            if (lane == 0) red[wv] = mx;
            __syncthreads();
            mx = red[0];
#pragma unroll
            for (int w = 1; w < 8; ++w) mx = fmaxf(mx, red[w]);
            float ex = (tid < CP) ? __expf(ev - mx) : 0.f;
            float sm = ex;
#pragma unroll
            for (int o = 32; o; o >>= 1) sm += __shfl_down(sm, o);
            if (lane == 0) red[8 + wv] = sm;
            __syncthreads();
            sm = red[8];
#pragma unroll
            for (int w = 1; w < 8; ++w) sm += red[8 + w];
            float al = ex / sm;
            if (tid < CP) {
                als[tid] = al;
                if (tid >= 49 * q && tid < 49 * (q + 1))
                    alph[(size_t)batt * (CT * CP) + t * CP + tid] = ((lb - 1) > t) ? al : 0.f;
            }
        }
        __syncthreads();
        {
            float aw[8] = {};
#pragma unroll
            for (int it = 0; it < 7; ++it) {
                int p = it * 32 + wv * 4 + ar_;
                if (p < CP) {
                    float a = als[p];
#pragma unroll
                    for (int j = 0; j < 8; ++j) aw[j] = fmaf(a, (float)er[it][j], aw[j]);
                }
            }
#pragma unroll
            for (int j = 0; j < 8; ++j) awp[wv * 4 + ar_][ac_ * 8 + j] = aw[j];
        }
        __syncthreads();
        if (tid < 128) {
            float sv = 0.f;
#pragma unroll
            for (int g = 0; g < 32; ++g) sv += awp[g][tid];
            ast_f(&xxa[batt * 512 + 128 * q + tid], sigf(ga_s[tid]) * sv);
        }
        post16(sl + 16 + s, t + 1);

        // prefetch next 12 phase-4 weight chunks -- overlaps s3 poll
        uint4 w4p[12];
#pragma unroll
        for (int j = 0; j < 12; ++j)
            w4p[j] = *(const uint4*)(wp4 + (size_t)(12 + j) * 1024);

        wait16(sl + 16, t + 1);
        // build xh_s[4][1024] = [xawe; h] per batch
#pragma unroll
        for (int k = 0; k < 4; ++k) {
            int c4 = k * 512 + tid;
            int bb = c4 >> 9, j = c4 & 511;
            xh_s[bb * 1024 + j] = (f16)ald_f(&xxa[(b0 + bb) * 512 + j]);
        }
#pragma unroll
        for (int k = 0; k < 2; ++k) {
            int u = k * 512 + tid;
            int bb = u >> 8, jj = u & 255;
            ((unsigned*)xh_s)[bb * 512 + 256 + jj] = ((unsigned*)h_s)[bb * 256 + jj];
        }
        __syncthreads();

        // ---- phase 4: gates c=[128s,128s+128) x 4 batches (K-split 4) ----
        {
            const uint4* xq = (const uint4*)xh_s;
            float a0 = 0.f, a1 = 0.f, a2 = 0.f, a3 = 0.f;
            auto step4 = [&](uint4 w, int kk4) {
                uint4 x0 = xq[kk4], x1 = xq[128 + kk4], x2 = xq[256 + kk4], x3 = xq[384 + kk4];
                a0 = dotp(asf16x2(w.x), asf16x2(x0.x), a0);
                a1 = dotp(asf16x2(w.x), asf16x2(x1.x), a1);
                a2 = dotp(asf16x2(w.x), asf16x2(x2.x), a2);
                a3 = dotp(asf16x2(w.x), asf16x2(x3.x), a3);
                a0 = dotp(asf16x2(w.y), asf16x2(x0.y), a0);
                a1 = dotp(asf16x2(w.y), asf16x2(x1.y), a1);
                a2 = dotp(asf16x2(w.y), asf16x2(x2.y), a2);
                a3 = dotp(asf16x2(w.y), asf16x2(x3.y), a3);
                a0 = dotp(asf16x2(w.z), asf16x2(x0.z), a0);
                a1 = dotp(asf16x2(w.z), asf16x2(x1.z), a1);
                a2 = dotp(asf16x2(w.z), asf16x2(x2.z), a2);
                a3 = dotp(asf16x2(w.z), asf16x2(x3.z), a3);
                a0 = dotp(asf16x2(w.w), asf16x2(x0.w), a0);
                a1 = dotp(asf16x2(w.w), asf16x2(x1.w), a1);
                a2 = dotp(asf16x2(w.w), asf16x2(x2.w), a2);
                a3 = dotp(asf16x2(w.w), asf16x2(x3.w), a3);
            };
#pragma unroll
            for (int i = 0; i < 12; ++i) step4(w4h[i], ks4 * 32 + i);
#pragma unroll
            for (int i = 0; i < 12; ++i) step4(w4p[i], ks4 * 32 + 12 + i);
#pragma unroll
            for (int i = 24; i < 32; ++i)
                step4(*(const uint4*)(wp4 + (size_t)i * 1024), ks4 * 32 + i);
            f32x4 pk; pk[0] = a0; pk[1] = a1; pk[2] = a2; pk[3] = a3;
            *(f32x4*)&part[ks4 * 512 + o4 * 4] = pk;
        }
        __syncthreads();
        {
            float g = part[tid] + part[512 + tid] + part[1024 + tid] + part[1536 + tid];
            int o = tid >> 2, bb = tid & 3;
            gt[tid] = g + embIH[(size_t)(t * 64 + b0 + bb) * 2048 + 128 * s + o];
        }
        __syncthreads();
        if (tid < 128) {
            int dd = tid >> 2, bb = tid & 3;
            float gi = gt[(4 * dd + 0) * 4 + bb];
            float gf = gt[(4 * dd + 1) * 4 + bb];
            float gg = gt[(4 * dd + 2) * 4 + bb];
            float go = gt[(4 * dd + 3) * 4 + bb];
            float cn = sigf(gf) * c_s[bb * 32 + dd] + sigf(gi) * tanhf(gg);
            c_s[bb * 32 + dd] = cn;
            htmp[bb * 32 + dd] = (f16)(sigf(go) * tanhf(cn));
        }
        __syncthreads();
        if (tid < 64) {
            int bb = tid >> 4, dd2 = (tid & 15) * 2;
            union { f16 h[2]; unsigned u; } pk;
            pk.h[0] = htmp[bb * 32 + dd2]; pk.h[1] = htmp[bb * 32 + dd2 + 1];
            size_t off = (size_t)(t + 1) * 32768 + (b0 + bb) * 512 + 32 * s + dd2;
            ast_u((unsigned*)hbuf + (off >> 1), pk.u);
        }
        post16(sl + 32 + s, t + 1);
    }
}

// ---------------------------------------------------------------------------
extern "C" void kernel_launch(void* const* d_in, const int* in_sizes, int n_in,
                              void* d_out, int out_size, void* d_ws, size_t ws_size,
                              hipStream_t stream)
{
    const float* enc  = (const float*)d_in[0];
    const int*   caps = (const int*)d_in[1];
    const int*   lens = (const int*)d_in[2];
    const float* emb  = (const float*)d_in[3];
    const float* W_ea = (const float*)d_in[4];
    const float* b_ea = (const float*)d_in[5];
    const float* W_da = (const float*)d_in[6];
    const float* b_da = (const float*)d_in[7];
    const float* W_fa = (const float*)d_in[8];
    const float* b_fa = (const float*)d_in[9];
    const float* W_fb = (const float*)d_in[10];
    const float* b_fb = (const float*)d_in[11];
    const float* W_ih = (const float*)d_in[12];
    const float* W_hh = (const float*)d_in[13];
    const float* b_ih = (const float*)d_in[14];
    const float* b_hh = (const float*)d_in[15];
    const float* W_fc = (const float*)d_in[16];
    const float* b_fc = (const float*)d_in[17];

    float* out = (float*)d_out;
    float* alph_out = out + (size_t)CB * CT * CV;

    char* p = (char*)d_ws;
    auto carve = [&](size_t bytes) {
        char* r = p;
        p += (bytes + 255) & ~(size_t)255;
        return r;
    };
    f16* enc_h   = (f16*)carve((size_t)12544 * 512 * 2);
    f16* att1_h  = (f16*)carve((size_t)12544 * 512 * 2);
    f16* Wea_h   = (f16*)carve((size_t)512 * 512 * 2);
    f16* W1L     = (f16*)carve((size_t)16 * 64 * 64 * 8 * 2);    // 1 MB
    f16* BpL     = (f16*)carve((size_t)16 * 128 * 128 * 8 * 2);  // 4 MB
    f16* WihE_p  = (f16*)carve((size_t)2048 * 512 * 2);
    f16* Wfc_h   = (f16*)carve((size_t)CVP * 512 * 2);
    f16* embg    = (f16*)carve((size_t)1280 * 512 * 2);
    float* embIH = (float*)carve((size_t)1280 * 2048 * 4);
    float* bcat  = (float*)carve(1024 * 4);
    float* bsum_p= (float*)carve(2048 * 4);
    f16* hbuf    = (f16*)carve((size_t)21 * 64 * 512 * 2);
    float* cinit = (float*)carve((size_t)64 * 512 * 4);
    float* xatt2 = (float*)carve((size_t)64 * 1024 * 4);
    float* xxa   = (float*)carve((size_t)64 * 512 * 4);
    int* gsync   = (int*)carve(1024 * 4);

    hipLaunchKernelGGL(k_mega, dim3(4096), dim3(256), 0, stream,
                       enc, W_ea, W_da, W_fb, W_ih, W_hh, W_fc, emb, caps,
                       b_da, b_fb, b_ih, b_hh,
                       enc_h, Wea_h, W1L, BpL, WihE_p, Wfc_h, embg, bcat, bsum_p, gsync);

    hipLaunchKernelGGL(k_h0, dim3(64), dim3(256), 0, stream, enc, hbuf, cinit);

    // att1 = enc_h @ W_ea^T + b_ea  (M=12544, N=512) -> f16
    hipLaunchKernelGGL((gemm_k512<EPI_F16B>), dim3(4, 98), dim3(256), 0, stream,
                       enc_h, Wea_h, 512, b_ea, (float*)nullptr, att1_h, (const int*)nullptr);
    // embIH = embg @ WihE_p^T + bsum_p  (M=1280, N=2048 permuted c=4d+g) -> f32
    hipLaunchKernelGGL((gemm_k512<EPI_F32B>), dim3(16, 10), dim3(256), 0, stream,
                       embg, WihE_p, 2048, bsum_p, embIH, (f16*)nullptr, (const int*)nullptr);

    // 20-step recurrence: 16 quads x 16 slices, 3 slot syncs/step
    hipLaunchKernelGGL(k_loopQ, dim3(256), dim3(512), 0, stream,
                       att1_h, enc_h, W1L, BpL, embIH, W_fa, b_fa, bcat,
                       lens, cinit, hbuf, alph_out, xatt2, xxa, gsync);

    // predictions = h(1..20) @ W_fc^T + b_fc, masked scatter (XCD-pinned swizzle)
    hipLaunchKernelGGL((gemm_k512<EPI_PREDS>), dim3(2400), dim3(256), 0, stream,
                       hbuf + 32768, Wfc_h, CVP, b_fc, out, (f16*)nullptr, lens);
}

// Round 14
// 1004.654 us; speedup vs baseline: 1.5952x; 1.5952x over previous
//
#include <hip/hip_runtime.h>
#include <hip/hip_bf16.h>

typedef _Float16 f16;
typedef __attribute__((ext_vector_type(8))) _Float16 f16x8;
typedef __attribute__((ext_vector_type(2))) _Float16 f16x2;
typedef __attribute__((ext_vector_type(4))) float f32x4;

constexpr int CB = 64, CP = 196, CH = 512, CV = 30000, CVP = 30080, CT = 20;
constexpr int NT = 235;  // preds col tiles

__device__ __forceinline__ float sigf(float x) { return 1.f / (1.f + __expf(-x)); }

#if defined(__has_builtin)
#if __has_builtin(__builtin_amdgcn_fdot2)
#define HAVE_FDOT2 1
#endif
#endif

__device__ __forceinline__ f16x2 asf16x2(unsigned u) {
    union { unsigned x; f16x2 h; } c; c.x = u; return c.h;
}
__device__ __forceinline__ float dotp(f16x2 a, f16x2 b, float c) {
#ifdef HAVE_FDOT2
    return __builtin_amdgcn_fdot2(a, b, c, false);
#else
    return fmaf((float)a[0], (float)b[0], fmaf((float)a[1], (float)b[1], c));
#endif
}

// ---- relaxed agent-scope (sc1, L3-coherent) helpers
__device__ __forceinline__ unsigned ald_u(const unsigned* p) {
    return __hip_atomic_load(p, __ATOMIC_RELAXED, __HIP_MEMORY_SCOPE_AGENT);
}
__device__ __forceinline__ void ast_u(unsigned* p, unsigned v) {
    __hip_atomic_store(p, v, __ATOMIC_RELAXED, __HIP_MEMORY_SCOPE_AGENT);
}
__device__ __forceinline__ float ald_f(const float* p) {
    return __hip_atomic_load(p, __ATOMIC_RELAXED, __HIP_MEMORY_SCOPE_AGENT);
}
__device__ __forceinline__ void ast_f(float* p, float v) {
    __hip_atomic_store(p, v, __ATOMIC_RELAXED, __HIP_MEMORY_SCOPE_AGENT);
}

// ---- 16-producer slot sync (one 64B line per sync point per quad).
__device__ __forceinline__ void wait16(const int* base, int target) {
    if (threadIdx.x < 64) {
        for (;;) {
            int v = __hip_atomic_load(base + (threadIdx.x & 15), __ATOMIC_RELAXED,
                                      __HIP_MEMORY_SCOPE_AGENT);
            if (__all(v >= target)) break;
            __builtin_amdgcn_s_sleep(1);
        }
    }
    __builtin_amdgcn_s_barrier();   // raw barrier: does NOT drain vmcnt
    __builtin_amdgcn_sched_barrier(0);
}
__device__ __forceinline__ void post16(int* slot, int val) {
    __syncthreads();
    if (threadIdx.x == 0)
        __hip_atomic_store(slot, val, __ATOMIC_RELAXED, __HIP_MEMORY_SCOPE_AGENT);
}

// ---------------------------------------------------------------------------
// mega convert/transpose/prep kernel (one-time prologue)
//   W1L[s(16)][kk4(64)][o(64)][8] : global out O=64s+o; O<512 -> att2 dim O
//   BpL[s(16)][kk4(128)][o(128)][8]: c = 128s+o (c=4d+g); K=[xawe;h]
//   WihE_p[c][512]                 : c = 4d+g rows of W_ih cols 0..511
// ---------------------------------------------------------------------------
__device__ __forceinline__ void cvt8(const float* __restrict__ s, f16* __restrict__ d) {
    float4 a = *(const float4*)s;
    float4 b = *(const float4*)(s + 4);
    f16x8 o;
    o[0] = (f16)a.x; o[1] = (f16)a.y; o[2] = (f16)a.z; o[3] = (f16)a.w;
    o[4] = (f16)b.x; o[5] = (f16)b.y; o[6] = (f16)b.z; o[7] = (f16)b.w;
    *(f16x8*)d = o;
}

__global__ __launch_bounds__(256) void k_mega(
    const float* __restrict__ enc, const float* __restrict__ W_ea,
    const float* __restrict__ W_da, const float* __restrict__ W_fb,
    const float* __restrict__ W_ih, const float* __restrict__ W_hh,
    const float* __restrict__ W_fc, const float* __restrict__ emb,
    const int* __restrict__ caps, const float* __restrict__ b_da,
    const float* __restrict__ b_fb, const float* __restrict__ b_ih,
    const float* __restrict__ b_hh,
    f16* __restrict__ enc_h, f16* __restrict__ Wea_h, f16* __restrict__ W1L,
    f16* __restrict__ BpL, f16* __restrict__ WihE_p, f16* __restrict__ Wfc_h,
    f16* __restrict__ embg, float* __restrict__ bcat, float* __restrict__ bsum_p,
    int* __restrict__ gsync)
{
    constexpr long long E0 = 802816;            // enc cvt
    constexpr long long E1 = E0 + 32768;        // W_ea
    constexpr long long E2 = E1 + 1920000;      // W_fc
    constexpr long long E3 = E2 + 5120;         // Wfc pad zeros
    constexpr long long E4 = E3 + 81920;        // emb gather
    constexpr long long E5 = E4 + 65536;        // W1L  (16s x 64kk4 x 64o)
    constexpr long long E6 = E5 + 262144;       // BpL  (16s x 128kk4 x 128o)
    constexpr long long E7 = E6 + 131072;       // WihE_p (2048c x 64)
    constexpr long long E8 = E7 + 3072;         // biases
    constexpr long long TOT = E8 + 1024;        // gsync zero

    for (long long id = (long long)blockIdx.x * 256 + threadIdx.x; id < TOT;
         id += (long long)gridDim.x * 256) {
        if (id < E0) {
            cvt8(enc + id * 8, enc_h + id * 8);
        } else if (id < E1) {
            long long c = id - E0; cvt8(W_ea + c * 8, Wea_h + c * 8);
        } else if (id < E2) {
            long long c = id - E1; cvt8(W_fc + c * 8, Wfc_h + c * 8);
        } else if (id < E3) {
            long long c = id - E2; f16x8 z = {};
            *(f16x8*)&Wfc_h[15360000 + c * 8] = z;
        } else if (id < E4) {
            long long c = id - E3; int m = (int)(c >> 6), j = (int)(c & 63);
            int tt = m >> 6, bb = m & 63;
            int row = caps[bb * 21 + tt];
            cvt8(emb + (size_t)row * 512 + j * 8, embg + (size_t)m * 512 + j * 8);
        } else if (id < E5) {
            long long c = id - E4;
            int o = (int)(c & 63), kk4 = (int)((c >> 6) & 63), s = (int)(c >> 12);
            int O = 64 * s + o;
            const float* src = (O < 512) ? &W_da[(size_t)O * 512]
                                         : &W_fb[(size_t)(O - 512) * 512];
            cvt8(src + kk4 * 8, &W1L[(((size_t)s * 64 + kk4) * 64 + o) * 8]);
        } else if (id < E6) {
            long long c = id - E5;
            int o = (int)(c & 127), kk4 = (int)((c >> 7) & 127), s = (int)(c >> 14);
            int d = 32 * s + (o >> 2), g = o & 3;
            int r = g * 512 + d;
            const float* src = (kk4 < 64) ? &W_ih[(size_t)r * 1024 + 512 + kk4 * 8]
                                          : &W_hh[(size_t)r * 512 + (kk4 - 64) * 8];
            cvt8(src, &BpL[(((size_t)s * 128 + kk4) * 128 + o) * 8]);
        } else if (id < E7) {
            long long c = id - E6;
            int cc = (int)(c >> 6), j8 = (int)(c & 63);
            int r = (cc & 3) * 512 + (cc >> 2);
            cvt8(W_ih + (size_t)r * 1024 + j8 * 8, WihE_p + (size_t)cc * 512 + j8 * 8);
        } else if (id < E8) {
            int i = (int)(id - E7);
            if (i < 512) bcat[i] = b_da[i];
            else if (i < 1024) bcat[i] = b_fb[i - 512];
            else {
                int cc = i - 1024;
                int r = (cc & 3) * 512 + (cc >> 2);
                bsum_p[cc] = b_ih[r] + b_hh[r];
            }
        } else {
            gsync[(int)(id - E8)] = 0;
        }
    }
}

// h0 = mean_p(enc) -> hbuf slot 0 (f16) and cinit (f32)
__global__ __launch_bounds__(256) void k_h0(const float* __restrict__ enc,
                                            f16* __restrict__ hbuf, float* __restrict__ cinit)
{
    int b = blockIdx.x;
    for (int h = threadIdx.x; h < CH; h += 256) {
        const float* p = enc + (size_t)b * CP * CH + h;
        float s = 0.f;
        for (int q = 0; q < CP; ++q) s += p[q * CH];
        s *= (1.f / 196.f);
        hbuf[b * CH + h] = (f16)s;
        cinit[b * CH + h] = s;
    }
}

// ---------------------------------------------------------------------------
// K=512 GEMM: tile 128x128, BK=32, padded LDS, reg prefetch.
// EPI_PREDS: 1-D grid 2400 with XCD-pinning swizzle (B tile L2-resident).
// ---------------------------------------------------------------------------
enum { EPI_F16B = 0, EPI_F32B = 1, EPI_PREDS = 2 };

template <int EPI>
__global__ __launch_bounds__(256) void gemm_k512(
    const f16* __restrict__ Aptr, const f16* __restrict__ Bptr, int N,
    const float* __restrict__ bias, float* __restrict__ Cf,
    f16* __restrict__ Ch, const int* __restrict__ lengths)
{
    constexpr int LD = 40;
    const int tid = threadIdx.x;
    const int lane = tid & 63, wave = tid >> 6;
    const int wr = wave >> 1, wc = wave & 1;
    int bx, by;
    if constexpr (EPI == EPI_PREDS) {
        int bid1 = blockIdx.x;
        int nt = (bid1 / 80) * 8 + (bid1 & 7);
        int mt = (bid1 >> 3) % 10;
        if (nt >= NT) return;
        bx = nt; by = mt;
    } else {
        bx = blockIdx.x; by = blockIdx.y;
    }

    __shared__ f16 As[128 * LD];
    __shared__ f16 Bs[128 * LD];

    const f16* Ag = Aptr + (size_t)by * 128 * 512;
    const f16* Bg = Bptr + (size_t)bx * 128 * 512;

    int srow[2], skc[2];
#pragma unroll
    for (int i = 0; i < 2; ++i) { int ci = tid + i * 256; srow[i] = ci >> 2; skc[i] = (ci & 3) * 8; }

    f32x4 acc[4][4] = {};
    f16x8 ar[2], br[2];
#pragma unroll
    for (int i = 0; i < 2; ++i) {
        ar[i] = *(const f16x8*)&Ag[(size_t)srow[i] * 512 + skc[i]];
        br[i] = *(const f16x8*)&Bg[(size_t)srow[i] * 512 + skc[i]];
    }

    const int rr = lane & 15, kg = (lane >> 4) * 8;
    for (int kt = 0; kt < 16; ++kt) {
        __syncthreads();
#pragma unroll
        for (int i = 0; i < 2; ++i) {
            *(f16x8*)&As[srow[i] * LD + skc[i]] = ar[i];
            *(f16x8*)&Bs[srow[i] * LD + skc[i]] = br[i];
        }
        __syncthreads();
        if (kt < 15) {
            int k0 = (kt + 1) * 32;
#pragma unroll
            for (int i = 0; i < 2; ++i) {
                ar[i] = *(const f16x8*)&Ag[(size_t)srow[i] * 512 + k0 + skc[i]];
                br[i] = *(const f16x8*)&Bg[(size_t)srow[i] * 512 + k0 + skc[i]];
            }
        }
        f16x8 af[4], bf[4];
#pragma unroll
        for (int mi = 0; mi < 4; ++mi) af[mi] = *(const f16x8*)&As[(wr * 64 + mi * 16 + rr) * LD + kg];
#pragma unroll
        for (int ni = 0; ni < 4; ++ni) bf[ni] = *(const f16x8*)&Bs[(wc * 64 + ni * 16 + rr) * LD + kg];
#pragma unroll
        for (int mi = 0; mi < 4; ++mi)
#pragma unroll
            for (int ni = 0; ni < 4; ++ni)
                acc[mi][ni] = __builtin_amdgcn_mfma_f32_16x16x32_f16(af[mi], bf[ni], acc[mi][ni], 0, 0, 0);
    }

    const int m0 = by * 128 + wr * 64;
    const int n0 = bx * 128 + wc * 64;
    const int r0 = (lane >> 4) * 4, cc = lane & 15;
#pragma unroll
    for (int mi = 0; mi < 4; ++mi) {
#pragma unroll
        for (int ni = 0; ni < 4; ++ni) {
#pragma unroll
            for (int r = 0; r < 4; ++r) {
                int m = m0 + mi * 16 + r0 + r;
                int n = n0 + ni * 16 + cc;
                float v = acc[mi][ni][r];
                if constexpr (EPI == EPI_F16B) {
                    Ch[(size_t)m * N + n] = (f16)(v + bias[n]);
                } else if constexpr (EPI == EPI_F32B) {
                    Cf[(size_t)m * N + n] = v + bias[n];
                } else {
                    if (n < CV) {
                        int tt = m >> 6, b = m & 63;
                        float val = ((lengths[b] - 1) > tt) ? (v + bias[n]) : 0.f;
                        __builtin_nontemporal_store(val, &Cf[(size_t)b * (CT * CV) + (size_t)tt * CV + n]);
                    }
                }
            }
        }
    }
}

// ---------------------------------------------------------------------------
// Recurrence: 256 blocks = 16 quads (4 batches) x 16 out-slices, 512 threads.
// THREE sync points/step: s1 (att2), s3 (xawe), s4 (h).
// e is computed locally for ALL 196 rows (kills the old s2 sync); weights
// are STREAMED from L2 (r12-style) -- no register hoarding (r13 spilled).
// ---------------------------------------------------------------------------
__global__ __launch_bounds__(512) void k_loopQ(
    const f16* __restrict__ att1, const f16* __restrict__ ench,
    const f16* __restrict__ W1L, const f16* __restrict__ BpL,
    const float* __restrict__ embIH, const float* __restrict__ Wfa,
    const float* __restrict__ bfa, const float* __restrict__ bcat,
    const int* __restrict__ lens, const float* __restrict__ cinit,
    f16* __restrict__ hbuf, float* __restrict__ alph,
    float* __restrict__ xatt2, float* __restrict__ xxa, int* __restrict__ gsync)
{
    const int bid = blockIdx.x, tid = threadIdx.x;
    const int lane = tid & 63, wv = tid >> 6;
    const int q4 = bid >> 4, s = bid & 15;
    const int b0 = 4 * q4;
    const int batt = b0 + (s & 3), q = s >> 2;

    int* sl = gsync + q4 * 64;  // [s1|s3|s4] x 16

    __shared__ __align__(16) f16 h_s[4 * 512];
    __shared__ __align__(16) float part[2048];
    __shared__ float a2f[512], ga_s[128];
    __shared__ float es[200], als[200], red[16];
    __shared__ float awp[32][128];
    __shared__ __align__(16) f16 xh_s[4 * 1024];
    __shared__ float gt[512];
    __shared__ f16 htmp[128];
    __shared__ float c_s[128];

    ((unsigned*)h_s)[tid] = ((const unsigned*)(hbuf + b0 * 512))[tid];
    ((unsigned*)h_s)[tid + 512] = ((const unsigned*)(hbuf + b0 * 512))[tid + 512];
    if (tid < 128) c_s[tid] = cinit[(b0 + (tid >> 5)) * 512 + 32 * s + (tid & 31)];

    const float bfa0 = bfa[0];
    const int lb = lens[batt];
    float wfr[8];
#pragma unroll
    for (int j = 0; j < 8; ++j) wfr[j] = Wfa[lane * 8 + j];
    const int ar_ = lane >> 4, ac_ = lane & 15;
    const int ks1 = tid >> 6, o1 = tid & 63;     // phase1: K-split 8 x 64 outs
    const int ks4 = tid >> 7, o4 = tid & 127;    // phase4: K-split 4 x 128 outs
    const f16* wp1 = W1L + (((size_t)s * 64 + ks1 * 8) * 64 + o1) * 8;
    const f16* wp4 = BpL + (((size_t)s * 128 + ks4 * 32) * 128 + o4) * 8;
    __syncthreads();

    for (int t = 0; t < CT; ++t) {
        if (t > 0) {
            wait16(sl + 32, t);
            const unsigned* hp = (const unsigned*)(hbuf + (size_t)t * 32768 + b0 * 512);
            ((unsigned*)h_s)[tid] = ald_u(hp + tid);
            ((unsigned*)h_s)[tid + 512] = ald_u(hp + tid + 512);
            __syncthreads();
        }

        // ---- phase 1: att2+gate outs [64s,64s+64) x 4 batches (K-split 8) ----
        {
            const uint4* xq = (const uint4*)h_s;
            float a0 = 0.f, a1 = 0.f, a2 = 0.f, a3 = 0.f;
#pragma unroll 4
            for (int i = 0; i < 8; ++i) {
                uint4 w = *(const uint4*)(wp1 + (size_t)i * 512);
                int kk4 = ks1 * 8 + i;
                uint4 x0 = xq[kk4], x1 = xq[64 + kk4], x2 = xq[128 + kk4], x3 = xq[192 + kk4];
                a0 = dotp(asf16x2(w.x), asf16x2(x0.x), a0);
                a1 = dotp(asf16x2(w.x), asf16x2(x1.x), a1);
                a2 = dotp(asf16x2(w.x), asf16x2(x2.x), a2);
                a3 = dotp(asf16x2(w.x), asf16x2(x3.x), a3);
                a0 = dotp(asf16x2(w.y), asf16x2(x0.y), a0);
                a1 = dotp(asf16x2(w.y), asf16x2(x1.y), a1);
                a2 = dotp(asf16x2(w.y), asf16x2(x2.y), a2);
                a3 = dotp(asf16x2(w.y), asf16x2(x3.y), a3);
                a0 = dotp(asf16x2(w.z), asf16x2(x0.z), a0);
                a1 = dotp(asf16x2(w.z), asf16x2(x1.z), a1);
                a2 = dotp(asf16x2(w.z), asf16x2(x2.z), a2);
                a3 = dotp(asf16x2(w.z), asf16x2(x3.z), a3);
                a0 = dotp(asf16x2(w.w), asf16x2(x0.w), a0);
                a1 = dotp(asf16x2(w.w), asf16x2(x1.w), a1);
                a2 = dotp(asf16x2(w.w), asf16x2(x2.w), a2);
                a3 = dotp(asf16x2(w.w), asf16x2(x3.w), a3);
            }
            f32x4 pk; pk[0] = a0; pk[1] = a1; pk[2] = a2; pk[3] = a3;
            *(f32x4*)&part[ks1 * 256 + o1 * 4] = pk;
        }
        __syncthreads();
        if (tid < 256) {
            float v = 0.f;
#pragma unroll
            for (int w8 = 0; w8 < 8; ++w8) v += part[w8 * 256 + tid];
            int o = tid >> 2, bb = tid & 3;
            int O = 64 * s + o;
            ast_f(&xatt2[(size_t)(b0 + bb) * 1024 + O], v + bcat[O]);
        }
        post16(sl + s, t + 1);

        // prefetch first 8 att1 rows (p = wv + 8i, rows 0..63) -- overlaps s1 poll
        f16x8 fr[8];
#pragma unroll
        for (int i = 0; i < 8; ++i)
            fr[i] = *(const f16x8*)&att1[((size_t)batt * CP + wv + 8 * i) * 512 + lane * 8];

        wait16(sl, t + 1);
        a2f[tid] = ald_f(&xatt2[(size_t)batt * 1024 + tid]);
        if (tid < 128) ga_s[tid] = ald_f(&xatt2[(size_t)batt * 1024 + 512 + 128 * q + tid]);
        __syncthreads();

        // ---- phase 2 (local): e for ALL 196 rows of batt ----
        {
            float a2r[8];
#pragma unroll
            for (int j = 0; j < 8; ++j) a2r[j] = a2f[lane * 8 + j];
#pragma unroll
            for (int i = 0; i < 8; ++i) {
                float e = 0.f;
#pragma unroll
                for (int j = 0; j < 8; ++j)
                    e += fmaxf((float)fr[i][j] + a2r[j], 0.f) * wfr[j];
#pragma unroll
                for (int o = 32; o; o >>= 1) e += __shfl_down(e, o);
                if (lane == 0) es[wv + 8 * i] = e + bfa0;
            }
#pragma unroll 4
            for (int i = 8; i < 25; ++i) {
                int p = wv + 8 * i;
                if (p < CP) {
                    f16x8 av = *(const f16x8*)&att1[((size_t)batt * CP + p) * 512 + lane * 8];
                    float e = 0.f;
#pragma unroll
                    for (int j = 0; j < 8; ++j)
                        e += fmaxf((float)av[j] + a2r[j], 0.f) * wfr[j];
#pragma unroll
                    for (int o = 32; o; o >>= 1) e += __shfl_down(e, o);
                    if (lane == 0) es[p] = e + bfa0;
                }
            }
        }

        // prefetch enc awe fragments (lands during softmax)
        f16x8 er[7];
#pragma unroll
        for (int it = 0; it < 7; ++it) {
            int p = it * 32 + wv * 4 + ar_;
            if (p < CP)
                er[it] = *(const f16x8*)&ench[((size_t)batt * CP + p) * 512 + 128 * q + ac_ * 8];
        }
        __syncthreads();

        // ---- phase 3: softmax (local) + awe h-slice + xawe ----
        {
            float ev = (tid < CP) ? es[tid] : -1e30f;
            float mx = ev;
#pragma unroll
            for (int o = 32; o; o >>= 1) mx = fmaxf(mx, __shfl_down(mx, o));
            if (lane == 0) red[wv] = mx;
            __syncthreads();
            mx = red[0];
#pragma unroll
            for (int w = 1; w < 8; ++w) mx = fmaxf(mx, red[w]);
            float ex = (tid < CP) ? __expf(ev - mx) : 0.f;
            float sm = ex;
#pragma unroll
            for (int o = 32; o; o >>= 1) sm += __shfl_down(sm, o);
            if (lane == 0) red[8 + wv] = sm;
            __syncthreads();
            sm = red[8];
#pragma unroll
            for (int w = 1; w < 8; ++w) sm += red[8 + w];
            float al = ex / sm;
            if (tid < CP) {
                als[tid] = al;
                if (tid >= 49 * q && tid < 49 * (q + 1))
                    alph[(size_t)batt * (CT * CP) + t * CP + tid] = ((lb - 1) > t) ? al : 0.f;
            }
        }
        __syncthreads();
        {
            float aw[8] = {};
#pragma unroll
            for (int it = 0; it < 7; ++it) {
                int p = it * 32 + wv * 4 + ar_;
                if (p < CP) {
                    float a = als[p];
#pragma unroll
                    for (int j = 0; j < 8; ++j) aw[j] = fmaf(a, (float)er[it][j], aw[j]);
                }
            }
#pragma unroll
            for (int j = 0; j < 8; ++j) awp[wv * 4 + ar_][ac_ * 8 + j] = aw[j];
        }
        __syncthreads();
        if (tid < 128) {
            float sv = 0.f;
#pragma unroll
            for (int g = 0; g < 32; ++g) sv += awp[g][tid];
            ast_f(&xxa[batt * 512 + 128 * q + tid], sigf(ga_s[tid]) * sv);
        }
        post16(sl + 16 + s, t + 1);
        wait16(sl + 16, t + 1);
        // build xh_s[4][1024] = [xawe; h] per batch
#pragma unroll
        for (int k = 0; k < 4; ++k) {
            int c4 = k * 512 + tid;
            int bb = c4 >> 9, j = c4 & 511;
            xh_s[bb * 1024 + j] = (f16)ald_f(&xxa[(b0 + bb) * 512 + j]);
        }
#pragma unroll
        for (int k = 0; k < 2; ++k) {
            int u = k * 512 + tid;
            int bb = u >> 8, jj = u & 255;
            ((unsigned*)xh_s)[bb * 512 + 256 + jj] = ((unsigned*)h_s)[bb * 256 + jj];
        }
        __syncthreads();

        // ---- phase 4: gates c=[128s,128s+128) x 4 batches (K-split 4) ----
        {
            const uint4* xq = (const uint4*)xh_s;
            float a0 = 0.f, a1 = 0.f, a2 = 0.f, a3 = 0.f;
#pragma unroll 4
            for (int i = 0; i < 32; ++i) {
                uint4 w = *(const uint4*)(wp4 + (size_t)i * 1024);
                int kk4 = ks4 * 32 + i;
                uint4 x0 = xq[kk4], x1 = xq[128 + kk4], x2 = xq[256 + kk4], x3 = xq[384 + kk4];
                a0 = dotp(asf16x2(w.x), asf16x2(x0.x), a0);
                a1 = dotp(asf16x2(w.x), asf16x2(x1.x), a1);
                a2 = dotp(asf16x2(w.x), asf16x2(x2.x), a2);
                a3 = dotp(asf16x2(w.x), asf16x2(x3.x), a3);
                a0 = dotp(asf16x2(w.y), asf16x2(x0.y), a0);
                a1 = dotp(asf16x2(w.y), asf16x2(x1.y), a1);
                a2 = dotp(asf16x2(w.y), asf16x2(x2.y), a2);
                a3 = dotp(asf16x2(w.y), asf16x2(x3.y), a3);
                a0 = dotp(asf16x2(w.z), asf16x2(x0.z), a0);
                a1 = dotp(asf16x2(w.z), asf16x2(x1.z), a1);
                a2 = dotp(asf16x2(w.z), asf16x2(x2.z), a2);
                a3 = dotp(asf16x2(w.z), asf16x2(x3.z), a3);
                a0 = dotp(asf16x2(w.w), asf16x2(x0.w), a0);
                a1 = dotp(asf16x2(w.w), asf16x2(x1.w), a1);
                a2 = dotp(asf16x2(w.w), asf16x2(x2.w), a2);
                a3 = dotp(asf16x2(w.w), asf16x2(x3.w), a3);
            }
            f32x4 pk; pk[0] = a0; pk[1] = a1; pk[2] = a2; pk[3] = a3;
            *(f32x4*)&part[ks4 * 512 + o4 * 4] = pk;
        }
        __syncthreads();
        {
            float g = part[tid] + part[512 + tid] + part[1024 + tid] + part[1536 + tid];
            int o = tid >> 2, bb = tid & 3;
            gt[tid] = g + embIH[(size_t)(t * 64 + b0 + bb) * 2048 + 128 * s + o];
        }
        __syncthreads();
        if (tid < 128) {
            int dd = tid >> 2, bb = tid & 3;
            float gi = gt[(4 * dd + 0) * 4 + bb];
            float gf = gt[(4 * dd + 1) * 4 + bb];
            float gg = gt[(4 * dd + 2) * 4 + bb];
            float go = gt[(4 * dd + 3) * 4 + bb];
            float cn = sigf(gf) * c_s[bb * 32 + dd] + sigf(gi) * tanhf(gg);
            c_s[bb * 32 + dd] = cn;
            htmp[bb * 32 + dd] = (f16)(sigf(go) * tanhf(cn));
        }
        __syncthreads();
        if (tid < 64) {
            int bb = tid >> 4, dd2 = (tid & 15) * 2;
            union { f16 h[2]; unsigned u; } pk;
            pk.h[0] = htmp[bb * 32 + dd2]; pk.h[1] = htmp[bb * 32 + dd2 + 1];
            size_t off = (size_t)(t + 1) * 32768 + (b0 + bb) * 512 + 32 * s + dd2;
            ast_u((unsigned*)hbuf + (off >> 1), pk.u);
        }
        post16(sl + 32 + s, t + 1);
    }
}

// ---------------------------------------------------------------------------
extern "C" void kernel_launch(void* const* d_in, const int* in_sizes, int n_in,
                              void* d_out, int out_size, void* d_ws, size_t ws_size,
                              hipStream_t stream)
{
    const float* enc  = (const float*)d_in[0];
    const int*   caps = (const int*)d_in[1];
    const int*   lens = (const int*)d_in[2];
    const float* emb  = (const float*)d_in[3];
    const float* W_ea = (const float*)d_in[4];
    const float* b_ea = (const float*)d_in[5];
    const float* W_da = (const float*)d_in[6];
    const float* b_da = (const float*)d_in[7];
    const float* W_fa = (const float*)d_in[8];
    const float* b_fa = (const float*)d_in[9];
    const float* W_fb = (const float*)d_in[10];
    const float* b_fb = (const float*)d_in[11];
    const float* W_ih = (const float*)d_in[12];
    const float* W_hh = (const float*)d_in[13];
    const float* b_ih = (const float*)d_in[14];
    const float* b_hh = (const float*)d_in[15];
    const float* W_fc = (const float*)d_in[16];
    const float* b_fc = (const float*)d_in[17];

    float* out = (float*)d_out;
    float* alph_out = out + (size_t)CB * CT * CV;

    char* p = (char*)d_ws;
    auto carve = [&](size_t bytes) {
        char* r = p;
        p += (bytes + 255) & ~(size_t)255;
        return r;
    };
    f16* enc_h   = (f16*)carve((size_t)12544 * 512 * 2);
    f16* att1_h  = (f16*)carve((size_t)12544 * 512 * 2);
    f16* Wea_h   = (f16*)carve((size_t)512 * 512 * 2);
    f16* W1L     = (f16*)carve((size_t)16 * 64 * 64 * 8 * 2);    // 1 MB
    f16* BpL     = (f16*)carve((size_t)16 * 128 * 128 * 8 * 2);  // 4 MB
    f16* WihE_p  = (f16*)carve((size_t)2048 * 512 * 2);
    f16* Wfc_h   = (f16*)carve((size_t)CVP * 512 * 2);
    f16* embg    = (f16*)carve((size_t)1280 * 512 * 2);
    float* embIH = (float*)carve((size_t)1280 * 2048 * 4);
    float* bcat  = (float*)carve(1024 * 4);
    float* bsum_p= (float*)carve(2048 * 4);
    f16* hbuf    = (f16*)carve((size_t)21 * 64 * 512 * 2);
    float* cinit = (float*)carve((size_t)64 * 512 * 4);
    float* xatt2 = (float*)carve((size_t)64 * 1024 * 4);
    float* xxa   = (float*)carve((size_t)64 * 512 * 4);
    int* gsync   = (int*)carve(1024 * 4);

    hipLaunchKernelGGL(k_mega, dim3(4096), dim3(256), 0, stream,
                       enc, W_ea, W_da, W_fb, W_ih, W_hh, W_fc, emb, caps,
                       b_da, b_fb, b_ih, b_hh,
                       enc_h, Wea_h, W1L, BpL, WihE_p, Wfc_h, embg, bcat, bsum_p, gsync);

    hipLaunchKernelGGL(k_h0, dim3(64), dim3(256), 0, stream, enc, hbuf, cinit);

    // att1 = enc_h @ W_ea^T + b_ea  (M=12544, N=512) -> f16
    hipLaunchKernelGGL((gemm_k512<EPI_F16B>), dim3(4, 98), dim3(256), 0, stream,
                       enc_h, Wea_h, 512, b_ea, (float*)nullptr, att1_h, (const int*)nullptr);
    // embIH = embg @ WihE_p^T + bsum_p  (M=1280, N=2048 permuted c=4d+g) -> f32
    hipLaunchKernelGGL((gemm_k512<EPI_F32B>), dim3(16, 10), dim3(256), 0, stream,
                       embg, WihE_p, 2048, bsum_p, embIH, (f16*)nullptr, (const int*)nullptr);

    // 20-step recurrence: 16 quads x 16 slices, 3 slot syncs/step
    hipLaunchKernelGGL(k_loopQ, dim3(256), dim3(512), 0, stream,
                       att1_h, enc_h, W1L, BpL, embIH, W_fa, b_fa, bcat,
                       lens, cinit, hbuf, alph_out, xatt2, xxa, gsync);

    // predictions = h(1..20) @ W_fc^T + b_fc, masked scatter (XCD-pinned swizzle)
    hipLaunchKernelGGL((gemm_k512<EPI_PREDS>), dim3(2400), dim3(256), 0, stream,
                       hbuf + 32768, Wfc_h, CVP, b_fc, out, (f16*)nullptr, lens);
}

// Round 15
// 485.218 us; speedup vs baseline: 3.3028x; 2.0705x over previous
//
#include <hip/hip_runtime.h>
#include <hip/hip_bf16.h>

typedef _Float16 f16;
typedef __attribute__((ext_vector_type(8))) _Float16 f16x8;
typedef __attribute__((ext_vector_type(2))) _Float16 f16x2;
typedef __attribute__((ext_vector_type(4))) float f32x4;

constexpr int CB = 64, CP = 196, CH = 512, CV = 30000, CVP = 30080, CT = 20;
constexpr int NT = 235;  // preds col tiles

__device__ __forceinline__ float sigf(float x) { return 1.f / (1.f + __expf(-x)); }

#if defined(__has_builtin)
#if __has_builtin(__builtin_amdgcn_fdot2)
#define HAVE_FDOT2 1
#endif
#endif

__device__ __forceinline__ f16x2 asf16x2(unsigned u) {
    union { unsigned x; f16x2 h; } c; c.x = u; return c.h;
}
__device__ __forceinline__ float dotp(f16x2 a, f16x2 b, float c) {
#ifdef HAVE_FDOT2
    return __builtin_amdgcn_fdot2(a, b, c, false);
#else
    return fmaf((float)a[0], (float)b[0], fmaf((float)a[1], (float)b[1], c));
#endif
}

// ---- relaxed agent-scope (sc1, L3-coherent) helpers
__device__ __forceinline__ unsigned ald_u(const unsigned* p) {
    return __hip_atomic_load(p, __ATOMIC_RELAXED, __HIP_MEMORY_SCOPE_AGENT);
}
__device__ __forceinline__ void ast_u(unsigned* p, unsigned v) {
    __hip_atomic_store(p, v, __ATOMIC_RELAXED, __HIP_MEMORY_SCOPE_AGENT);
}
__device__ __forceinline__ float ald_f(const float* p) {
    return __hip_atomic_load(p, __ATOMIC_RELAXED, __HIP_MEMORY_SCOPE_AGENT);
}
__device__ __forceinline__ void ast_f(float* p, float v) {
    __hip_atomic_store(p, v, __ATOMIC_RELAXED, __HIP_MEMORY_SCOPE_AGENT);
}

// ---- 16-producer slot sync (one 64B line per sync point per quad).
__device__ __forceinline__ void wait16(const int* base, int target) {
    if (threadIdx.x < 64) {
        for (;;) {
            int v = __hip_atomic_load(base + (threadIdx.x & 15), __ATOMIC_RELAXED,
                                      __HIP_MEMORY_SCOPE_AGENT);
            if (__all(v >= target)) break;
            __builtin_amdgcn_s_sleep(1);
        }
    }
    __builtin_amdgcn_s_barrier();   // raw barrier: does NOT drain vmcnt
    __builtin_amdgcn_sched_barrier(0);
}
__device__ __forceinline__ void post16(int* slot, int val) {
    __syncthreads();
    if (threadIdx.x == 0)
        __hip_atomic_store(slot, val, __ATOMIC_RELAXED, __HIP_MEMORY_SCOPE_AGENT);
}

// ---------------------------------------------------------------------------
// mega convert/transpose/prep kernel (one-time prologue)
//   W1L[s(16)][kk4(64)][o(64)][8] : global out O=64s+o; O<512 -> att2 dim O
//   BpL[s(16)][kk4(128)][o(128)][8]: c = 128s+o (c=4d+g); K=[xawe;h]
//   WihE_p[c][512]                 : c = 4d+g rows of W_ih cols 0..511
// ---------------------------------------------------------------------------
__device__ __forceinline__ void cvt8(const float* __restrict__ s, f16* __restrict__ d) {
    float4 a = *(const float4*)s;
    float4 b = *(const float4*)(s + 4);
    f16x8 o;
    o[0] = (f16)a.x; o[1] = (f16)a.y; o[2] = (f16)a.z; o[3] = (f16)a.w;
    o[4] = (f16)b.x; o[5] = (f16)b.y; o[6] = (f16)b.z; o[7] = (f16)b.w;
    *(f16x8*)d = o;
}

__global__ __launch_bounds__(256) void k_mega(
    const float* __restrict__ enc, const float* __restrict__ W_ea,
    const float* __restrict__ W_da, const float* __restrict__ W_fb,
    const float* __restrict__ W_ih, const float* __restrict__ W_hh,
    const float* __restrict__ W_fc, const float* __restrict__ emb,
    const int* __restrict__ caps, const float* __restrict__ b_da,
    const float* __restrict__ b_fb, const float* __restrict__ b_ih,
    const float* __restrict__ b_hh,
    f16* __restrict__ enc_h, f16* __restrict__ Wea_h, f16* __restrict__ W1L,
    f16* __restrict__ BpL, f16* __restrict__ WihE_p, f16* __restrict__ Wfc_h,
    f16* __restrict__ embg, float* __restrict__ bcat, float* __restrict__ bsum_p,
    int* __restrict__ gsync)
{
    constexpr long long E0 = 802816;            // enc cvt
    constexpr long long E1 = E0 + 32768;        // W_ea
    constexpr long long E2 = E1 + 1920000;      // W_fc
    constexpr long long E3 = E2 + 5120;         // Wfc pad zeros
    constexpr long long E4 = E3 + 81920;        // emb gather
    constexpr long long E5 = E4 + 65536;        // W1L  (16s x 64kk4 x 64o)
    constexpr long long E6 = E5 + 262144;       // BpL  (16s x 128kk4 x 128o)
    constexpr long long E7 = E6 + 131072;       // WihE_p (2048c x 64)
    constexpr long long E8 = E7 + 3072;         // biases
    constexpr long long TOT = E8 + 1024;        // gsync zero

    for (long long id = (long long)blockIdx.x * 256 + threadIdx.x; id < TOT;
         id += (long long)gridDim.x * 256) {
        if (id < E0) {
            cvt8(enc + id * 8, enc_h + id * 8);
        } else if (id < E1) {
            long long c = id - E0; cvt8(W_ea + c * 8, Wea_h + c * 8);
        } else if (id < E2) {
            long long c = id - E1; cvt8(W_fc + c * 8, Wfc_h + c * 8);
        } else if (id < E3) {
            long long c = id - E2; f16x8 z = {};
            *(f16x8*)&Wfc_h[15360000 + c * 8] = z;
        } else if (id < E4) {
            long long c = id - E3; int m = (int)(c >> 6), j = (int)(c & 63);
            int tt = m >> 6, bb = m & 63;
            int row = caps[bb * 21 + tt];
            cvt8(emb + (size_t)row * 512 + j * 8, embg + (size_t)m * 512 + j * 8);
        } else if (id < E5) {
            long long c = id - E4;
            int o = (int)(c & 63), kk4 = (int)((c >> 6) & 63), s = (int)(c >> 12);
            int O = 64 * s + o;
            const float* src = (O < 512) ? &W_da[(size_t)O * 512]
                                         : &W_fb[(size_t)(O - 512) * 512];
            cvt8(src + kk4 * 8, &W1L[(((size_t)s * 64 + kk4) * 64 + o) * 8]);
        } else if (id < E6) {
            long long c = id - E5;
            int o = (int)(c & 127), kk4 = (int)((c >> 7) & 127), s = (int)(c >> 14);
            int d = 32 * s + (o >> 2), g = o & 3;
            int r = g * 512 + d;
            const float* src = (kk4 < 64) ? &W_ih[(size_t)r * 1024 + 512 + kk4 * 8]
                                          : &W_hh[(size_t)r * 512 + (kk4 - 64) * 8];
            cvt8(src, &BpL[(((size_t)s * 128 + kk4) * 128 + o) * 8]);
        } else if (id < E7) {
            long long c = id - E6;
            int cc = (int)(c >> 6), j8 = (int)(c & 63);
            int r = (cc & 3) * 512 + (cc >> 2);
            cvt8(W_ih + (size_t)r * 1024 + j8 * 8, WihE_p + (size_t)cc * 512 + j8 * 8);
        } else if (id < E8) {
            int i = (int)(id - E7);
            if (i < 512) bcat[i] = b_da[i];
            else if (i < 1024) bcat[i] = b_fb[i - 512];
            else {
                int cc = i - 1024;
                int r = (cc & 3) * 512 + (cc >> 2);
                bsum_p[cc] = b_ih[r] + b_hh[r];
            }
        } else {
            gsync[(int)(id - E8)] = 0;
        }
    }
}

// h0 = mean_p(enc) -> hbuf slot 0 (f16) and cinit (f32)
__global__ __launch_bounds__(256) void k_h0(const float* __restrict__ enc,
                                            f16* __restrict__ hbuf, float* __restrict__ cinit)
{
    int b = blockIdx.x;
    for (int h = threadIdx.x; h < CH; h += 256) {
        const float* p = enc + (size_t)b * CP * CH + h;
        float s = 0.f;
        for (int q = 0; q < CP; ++q) s += p[q * CH];
        s *= (1.f / 196.f);
        hbuf[b * CH + h] = (f16)s;
        cinit[b * CH + h] = s;
    }
}

// ---------------------------------------------------------------------------
// K=512 GEMM: tile 128x128, BK=32, padded LDS, reg prefetch.
// EPI_PREDS: 1-D grid 2400 with XCD-pinning swizzle (B tile L2-resident).
// ---------------------------------------------------------------------------
enum { EPI_F16B = 0, EPI_F32B = 1, EPI_PREDS = 2 };

template <int EPI>
__global__ __launch_bounds__(256) void gemm_k512(
    const f16* __restrict__ Aptr, const f16* __restrict__ Bptr, int N,
    const float* __restrict__ bias, float* __restrict__ Cf,
    f16* __restrict__ Ch, const int* __restrict__ lengths)
{
    constexpr int LD = 40;
    const int tid = threadIdx.x;
    const int lane = tid & 63, wave = tid >> 6;
    const int wr = wave >> 1, wc = wave & 1;
    int bx, by;
    if constexpr (EPI == EPI_PREDS) {
        int bid1 = blockIdx.x;
        int nt = (bid1 / 80) * 8 + (bid1 & 7);
        int mt = (bid1 >> 3) % 10;
        if (nt >= NT) return;
        bx = nt; by = mt;
    } else {
        bx = blockIdx.x; by = blockIdx.y;
    }

    __shared__ f16 As[128 * LD];
    __shared__ f16 Bs[128 * LD];

    const f16* Ag = Aptr + (size_t)by * 128 * 512;
    const f16* Bg = Bptr + (size_t)bx * 128 * 512;

    int srow[2], skc[2];
#pragma unroll
    for (int i = 0; i < 2; ++i) { int ci = tid + i * 256; srow[i] = ci >> 2; skc[i] = (ci & 3) * 8; }

    f32x4 acc[4][4] = {};
    f16x8 ar[2], br[2];
#pragma unroll
    for (int i = 0; i < 2; ++i) {
        ar[i] = *(const f16x8*)&Ag[(size_t)srow[i] * 512 + skc[i]];
        br[i] = *(const f16x8*)&Bg[(size_t)srow[i] * 512 + skc[i]];
    }

    const int rr = lane & 15, kg = (lane >> 4) * 8;
    for (int kt = 0; kt < 16; ++kt) {
        __syncthreads();
#pragma unroll
        for (int i = 0; i < 2; ++i) {
            *(f16x8*)&As[srow[i] * LD + skc[i]] = ar[i];
            *(f16x8*)&Bs[srow[i] * LD + skc[i]] = br[i];
        }
        __syncthreads();
        if (kt < 15) {
            int k0 = (kt + 1) * 32;
#pragma unroll
            for (int i = 0; i < 2; ++i) {
                ar[i] = *(const f16x8*)&Ag[(size_t)srow[i] * 512 + k0 + skc[i]];
                br[i] = *(const f16x8*)&Bg[(size_t)srow[i] * 512 + k0 + skc[i]];
            }
        }
        f16x8 af[4], bf[4];
#pragma unroll
        for (int mi = 0; mi < 4; ++mi) af[mi] = *(const f16x8*)&As[(wr * 64 + mi * 16 + rr) * LD + kg];
#pragma unroll
        for (int ni = 0; ni < 4; ++ni) bf[ni] = *(const f16x8*)&Bs[(wc * 64 + ni * 16 + rr) * LD + kg];
#pragma unroll
        for (int mi = 0; mi < 4; ++mi)
#pragma unroll
            for (int ni = 0; ni < 4; ++ni)
                acc[mi][ni] = __builtin_amdgcn_mfma_f32_16x16x32_f16(af[mi], bf[ni], acc[mi][ni], 0, 0, 0);
    }

    const int m0 = by * 128 + wr * 64;
    const int n0 = bx * 128 + wc * 64;
    const int r0 = (lane >> 4) * 4, cc = lane & 15;
#pragma unroll
    for (int mi = 0; mi < 4; ++mi) {
#pragma unroll
        for (int ni = 0; ni < 4; ++ni) {
#pragma unroll
            for (int r = 0; r < 4; ++r) {
                int m = m0 + mi * 16 + r0 + r;
                int n = n0 + ni * 16 + cc;
                float v = acc[mi][ni][r];
                if constexpr (EPI == EPI_F16B) {
                    Ch[(size_t)m * N + n] = (f16)(v + bias[n]);
                } else if constexpr (EPI == EPI_F32B) {
                    Cf[(size_t)m * N + n] = v + bias[n];
                } else {
                    if (n < CV) {
                        int tt = m >> 6, b = m & 63;
                        float val = ((lengths[b] - 1) > tt) ? (v + bias[n]) : 0.f;
                        __builtin_nontemporal_store(val, &Cf[(size_t)b * (CT * CV) + (size_t)tt * CV + n]);
                    }
                }
            }
        }
    }
}

// ---------------------------------------------------------------------------
// Recurrence: 256 blocks = 16 quads (4 batches) x 16 out-slices, 512 threads.
// THREE sync points/step: s1 (att2+gate), s2' (unnormalized v/z), s4 (h).
// Softmax without max-subtraction (e is O(1)):
//   awe[b] = (Sum_q v_q) / (Sum_q z_q),  v_q = Sum_{p in q's 49 rows} exp(e_p)*enc[b,p,:]
// Each block reads only its 49 att1/enc rows (r12 footprint) and rebuilds
// xawe for all 4 batches locally after the v/z exchange.
// ---------------------------------------------------------------------------
__global__ __launch_bounds__(512) void k_loopQ(
    const f16* __restrict__ att1, const f16* __restrict__ ench,
    const f16* __restrict__ W1L, const f16* __restrict__ BpL,
    const float* __restrict__ embIH, const float* __restrict__ Wfa,
    const float* __restrict__ bfa, const float* __restrict__ bcat,
    const int* __restrict__ lens, const float* __restrict__ cinit,
    f16* __restrict__ hbuf, float* __restrict__ alph,
    float* __restrict__ xatt2, float* __restrict__ xvz, int* __restrict__ gsync)
{
    const int bid = blockIdx.x, tid = threadIdx.x;
    const int lane = tid & 63, wv = tid >> 6;
    const int q4 = bid >> 4, s = bid & 15;
    const int b0 = 4 * q4;
    const int batt = b0 + (s & 3), q = s >> 2;

    int* sl = gsync + q4 * 64;  // [s1|s2'|s4] x 16

    __shared__ __align__(16) f16 h_s[4 * 512];
    __shared__ __align__(16) float part[2048];
    __shared__ float a2f[512];
    __shared__ float esx[56], red[16], invZb[4];
    __shared__ float awp[8][512];
    __shared__ __align__(16) f16 xh_s[4 * 1024];
    __shared__ float gt[512];
    __shared__ f16 htmp[128];
    __shared__ float c_s[128];

    ((unsigned*)h_s)[tid] = ((const unsigned*)(hbuf + b0 * 512))[tid];
    ((unsigned*)h_s)[tid + 512] = ((const unsigned*)(hbuf + b0 * 512))[tid + 512];
    if (tid < 128) c_s[tid] = cinit[(b0 + (tid >> 5)) * 512 + 32 * s + (tid & 31)];

    const float bfa0 = bfa[0];
    const int lb = lens[batt];
    float wfr[8];
#pragma unroll
    for (int j = 0; j < 8; ++j) wfr[j] = Wfa[lane * 8 + j];
    const int ecnt = (56 - wv) >> 3;             // e rows this wave (7 or 6)
    const int ks1 = tid >> 6, o1 = tid & 63;     // phase1: K-split 8 x 64 outs
    const int ks4 = tid >> 7, o4 = tid & 127;    // phase4: K-split 4 x 128 outs
    const f16* wp1 = W1L + (((size_t)s * 64 + ks1 * 8) * 64 + o1) * 8;
    const f16* wp4 = BpL + (((size_t)s * 128 + ks4 * 32) * 128 + o4) * 8;
    __syncthreads();

    for (int t = 0; t < CT; ++t) {
        if (t > 0) {
            wait16(sl + 32, t);
            const unsigned* hp = (const unsigned*)(hbuf + (size_t)t * 32768 + b0 * 512);
            ((unsigned*)h_s)[tid] = ald_u(hp + tid);
            ((unsigned*)h_s)[tid + 512] = ald_u(hp + tid + 512);
            __syncthreads();
        }

        // ---- phase 1: att2+gate outs [64s,64s+64) x 4 batches (K-split 8) ----
        {
            const uint4* xq = (const uint4*)h_s;
            float a0 = 0.f, a1 = 0.f, a2 = 0.f, a3 = 0.f;
#pragma unroll 4
            for (int i = 0; i < 8; ++i) {
                uint4 w = *(const uint4*)(wp1 + (size_t)i * 512);
                int kk4 = ks1 * 8 + i;
                uint4 x0 = xq[kk4], x1 = xq[64 + kk4], x2 = xq[128 + kk4], x3 = xq[192 + kk4];
                a0 = dotp(asf16x2(w.x), asf16x2(x0.x), a0);
                a1 = dotp(asf16x2(w.x), asf16x2(x1.x), a1);
                a2 = dotp(asf16x2(w.x), asf16x2(x2.x), a2);
                a3 = dotp(asf16x2(w.x), asf16x2(x3.x), a3);
                a0 = dotp(asf16x2(w.y), asf16x2(x0.y), a0);
                a1 = dotp(asf16x2(w.y), asf16x2(x1.y), a1);
                a2 = dotp(asf16x2(w.y), asf16x2(x2.y), a2);
                a3 = dotp(asf16x2(w.y), asf16x2(x3.y), a3);
                a0 = dotp(asf16x2(w.z), asf16x2(x0.z), a0);
                a1 = dotp(asf16x2(w.z), asf16x2(x1.z), a1);
                a2 = dotp(asf16x2(w.z), asf16x2(x2.z), a2);
                a3 = dotp(asf16x2(w.z), asf16x2(x3.z), a3);
                a0 = dotp(asf16x2(w.w), asf16x2(x0.w), a0);
                a1 = dotp(asf16x2(w.w), asf16x2(x1.w), a1);
                a2 = dotp(asf16x2(w.w), asf16x2(x2.w), a2);
                a3 = dotp(asf16x2(w.w), asf16x2(x3.w), a3);
            }
            f32x4 pk; pk[0] = a0; pk[1] = a1; pk[2] = a2; pk[3] = a3;
            *(f32x4*)&part[ks1 * 256 + o1 * 4] = pk;
        }
        __syncthreads();
        if (tid < 256) {
            float v = 0.f;
#pragma unroll
            for (int w8 = 0; w8 < 8; ++w8) v += part[w8 * 256 + tid];
            int o = tid >> 2, bb = tid & 3;
            int O = 64 * s + o;
            ast_f(&xatt2[(size_t)(b0 + bb) * 1024 + O], v + bcat[O]);
        }
        post16(sl + s, t + 1);

        // prefetch my 49 att1 rows AND the matching enc rows (overlaps s1 poll)
        f16x8 fr[7], er[7];
#pragma unroll
        for (int i = 0; i < 7; ++i)
            if (i < ecnt) {
                int p = 49 * q + wv + 8 * i;
                fr[i] = *(const f16x8*)&att1[((size_t)batt * CP + p) * 512 + lane * 8];
                er[i] = *(const f16x8*)&ench[((size_t)batt * CP + p) * 512 + lane * 8];
            }

        wait16(sl, t + 1);
        a2f[tid] = ald_f(&xatt2[(size_t)batt * 1024 + tid]);
        __syncthreads();

        // ---- phase 2: e rows + unnormalized v/z partials (local) ----
        {
            float a2r[8];
#pragma unroll
            for (int j = 0; j < 8; ++j) a2r[j] = a2f[lane * 8 + j];
            float aw[8] = {};
            float zw = 0.f;
#pragma unroll
            for (int i = 0; i < 7; ++i)
                if (i < ecnt) {
                    float e = 0.f;
#pragma unroll
                    for (int j = 0; j < 8; ++j)
                        e += fmaxf((float)fr[i][j] + a2r[j], 0.f) * wfr[j];
#pragma unroll
                    for (int o = 32; o; o >>= 1) e += __shfl_down(e, o);
                    e = __shfl(e, 0);
                    float ee = __expf(e + bfa0);
                    if (lane == 0) esx[wv + 8 * i] = ee;
                    zw += ee;
#pragma unroll
                    for (int j = 0; j < 8; ++j) aw[j] = fmaf(ee, (float)er[i][j], aw[j]);
                }
            if (lane == 0) red[wv] = zw;
#pragma unroll
            for (int j = 0; j < 8; ++j) awp[wv][lane * 8 + j] = aw[j];
        }
        __syncthreads();
        {
            float vsum = 0.f;
#pragma unroll
            for (int w = 0; w < 8; ++w) vsum += awp[w][tid];
            ast_f(&xvz[((size_t)batt * 4 + q) * 520 + tid], vsum);
            if (tid == 0) {
                float z = 0.f;
#pragma unroll
                for (int w = 0; w < 8; ++w) z += red[w];
                ast_f(&xvz[((size_t)batt * 4 + q) * 520 + 512], z);
            }
        }
        post16(sl + 16 + s, t + 1);

        // gate args for 4 batches: s1 data, valid now -- read overlaps s2' poll
        float ga[4];
#pragma unroll
        for (int bb = 0; bb < 4; ++bb)
            ga[bb] = ald_f(&xatt2[(size_t)(b0 + bb) * 1024 + 512 + tid]);

        wait16(sl + 16, t + 1);
        if (tid < 4) {
            float z = 0.f;
#pragma unroll
            for (int q2 = 0; q2 < 4; ++q2)
                z += ald_f(&xvz[((size_t)(b0 + tid) * 4 + q2) * 520 + 512]);
            invZb[tid] = 1.f / z;
        }
        __syncthreads();
#pragma unroll
        for (int bb = 0; bb < 4; ++bb) {
            float v = 0.f;
#pragma unroll
            for (int q2 = 0; q2 < 4; ++q2)
                v += ald_f(&xvz[((size_t)(b0 + bb) * 4 + q2) * 520 + tid]);
            xh_s[bb * 1024 + tid] = (f16)(sigf(ga[bb]) * v * invZb[bb]);
        }
#pragma unroll
        for (int k = 0; k < 2; ++k) {
            int u = k * 512 + tid;
            int bb = u >> 8, jj = u & 255;
            ((unsigned*)xh_s)[bb * 512 + 256 + jj] = ((unsigned*)h_s)[bb * 256 + jj];
        }
        if (tid < 49) {
            float al = esx[tid] * invZb[s & 3];
            alph[(size_t)batt * (CT * CP) + t * CP + 49 * q + tid] =
                ((lb - 1) > t) ? al : 0.f;
        }
        __syncthreads();

        // ---- phase 4: gates c=[128s,128s+128) x 4 batches (K-split 4) ----
        {
            const uint4* xq = (const uint4*)xh_s;
            float a0 = 0.f, a1 = 0.f, a2 = 0.f, a3 = 0.f;
#pragma unroll 4
            for (int i = 0; i < 32; ++i) {
                uint4 w = *(const uint4*)(wp4 + (size_t)i * 1024);
                int kk4 = ks4 * 32 + i;
                uint4 x0 = xq[kk4], x1 = xq[128 + kk4], x2 = xq[256 + kk4], x3 = xq[384 + kk4];
                a0 = dotp(asf16x2(w.x), asf16x2(x0.x), a0);
                a1 = dotp(asf16x2(w.x), asf16x2(x1.x), a1);
                a2 = dotp(asf16x2(w.x), asf16x2(x2.x), a2);
                a3 = dotp(asf16x2(w.x), asf16x2(x3.x), a3);
                a0 = dotp(asf16x2(w.y), asf16x2(x0.y), a0);
                a1 = dotp(asf16x2(w.y), asf16x2(x1.y), a1);
                a2 = dotp(asf16x2(w.y), asf16x2(x2.y), a2);
                a3 = dotp(asf16x2(w.y), asf16x2(x3.y), a3);
                a0 = dotp(asf16x2(w.z), asf16x2(x0.z), a0);
                a1 = dotp(asf16x2(w.z), asf16x2(x1.z), a1);
                a2 = dotp(asf16x2(w.z), asf16x2(x2.z), a2);
                a3 = dotp(asf16x2(w.z), asf16x2(x3.z), a3);
                a0 = dotp(asf16x2(w.w), asf16x2(x0.w), a0);
                a1 = dotp(asf16x2(w.w), asf16x2(x1.w), a1);
                a2 = dotp(asf16x2(w.w), asf16x2(x2.w), a2);
                a3 = dotp(asf16x2(w.w), asf16x2(x3.w), a3);
            }
            f32x4 pk; pk[0] = a0; pk[1] = a1; pk[2] = a2; pk[3] = a3;
            *(f32x4*)&part[ks4 * 512 + o4 * 4] = pk;
        }
        __syncthreads();
        {
            float g = part[tid] + part[512 + tid] + part[1024 + tid] + part[1536 + tid];
            int o = tid >> 2, bb = tid & 3;
            gt[tid] = g + embIH[(size_t)(t * 64 + b0 + bb) * 2048 + 128 * s + o];
        }
        __syncthreads();
        if (tid < 128) {
            int dd = tid >> 2, bb = tid & 3;
            float gi = gt[(4 * dd + 0) * 4 + bb];
            float gf = gt[(4 * dd + 1) * 4 + bb];
            float gg = gt[(4 * dd + 2) * 4 + bb];
            float go = gt[(4 * dd + 3) * 4 + bb];
            float cn = sigf(gf) * c_s[bb * 32 + dd] + sigf(gi) * tanhf(gg);
            c_s[bb * 32 + dd] = cn;
            htmp[bb * 32 + dd] = (f16)(sigf(go) * tanhf(cn));
        }
        __syncthreads();
        if (tid < 64) {
            int bb = tid >> 4, dd2 = (tid & 15) * 2;
            union { f16 h[2]; unsigned u; } pk;
            pk.h[0] = htmp[bb * 32 + dd2]; pk.h[1] = htmp[bb * 32 + dd2 + 1];
            size_t off = (size_t)(t + 1) * 32768 + (b0 + bb) * 512 + 32 * s + dd2;
            ast_u((unsigned*)hbuf + (off >> 1), pk.u);
        }
        post16(sl + 32 + s, t + 1);
    }
}

// ---------------------------------------------------------------------------
extern "C" void kernel_launch(void* const* d_in, const int* in_sizes, int n_in,
                              void* d_out, int out_size, void* d_ws, size_t ws_size,
                              hipStream_t stream)
{
    const float* enc  = (const float*)d_in[0];
    const int*   caps = (const int*)d_in[1];
    const int*   lens = (const int*)d_in[2];
    const float* emb  = (const float*)d_in[3];
    const float* W_ea = (const float*)d_in[4];
    const float* b_ea = (const float*)d_in[5];
    const float* W_da = (const float*)d_in[6];
    const float* b_da = (const float*)d_in[7];
    const float* W_fa = (const float*)d_in[8];
    const float* b_fa = (const float*)d_in[9];
    const float* W_fb = (const float*)d_in[10];
    const float* b_fb = (const float*)d_in[11];
    const float* W_ih = (const float*)d_in[12];
    const float* W_hh = (const float*)d_in[13];
    const float* b_ih = (const float*)d_in[14];
    const float* b_hh = (const float*)d_in[15];
    const float* W_fc = (const float*)d_in[16];
    const float* b_fc = (const float*)d_in[17];

    float* out = (float*)d_out;
    float* alph_out = out + (size_t)CB * CT * CV;

    char* p = (char*)d_ws;
    auto carve = [&](size_t bytes) {
        char* r = p;
        p += (bytes + 255) & ~(size_t)255;
        return r;
    };
    f16* enc_h   = (f16*)carve((size_t)12544 * 512 * 2);
    f16* att1_h  = (f16*)carve((size_t)12544 * 512 * 2);
    f16* Wea_h   = (f16*)carve((size_t)512 * 512 * 2);
    f16* W1L     = (f16*)carve((size_t)16 * 64 * 64 * 8 * 2);    // 1 MB
    f16* BpL     = (f16*)carve((size_t)16 * 128 * 128 * 8 * 2);  // 4 MB
    f16* WihE_p  = (f16*)carve((size_t)2048 * 512 * 2);
    f16* Wfc_h   = (f16*)carve((size_t)CVP * 512 * 2);
    f16* embg    = (f16*)carve((size_t)1280 * 512 * 2);
    float* embIH = (float*)carve((size_t)1280 * 2048 * 4);
    float* bcat  = (float*)carve(1024 * 4);
    float* bsum_p= (float*)carve(2048 * 4);
    f16* hbuf    = (f16*)carve((size_t)21 * 64 * 512 * 2);
    float* cinit = (float*)carve((size_t)64 * 512 * 4);
    float* xatt2 = (float*)carve((size_t)64 * 1024 * 4);
    float* xvz   = (float*)carve((size_t)256 * 520 * 4);
    int* gsync   = (int*)carve(1024 * 4);

    hipLaunchKernelGGL(k_mega, dim3(4096), dim3(256), 0, stream,
                       enc, W_ea, W_da, W_fb, W_ih, W_hh, W_fc, emb, caps,
                       b_da, b_fb, b_ih, b_hh,
                       enc_h, Wea_h, W1L, BpL, WihE_p, Wfc_h, embg, bcat, bsum_p, gsync);

    hipLaunchKernelGGL(k_h0, dim3(64), dim3(256), 0, stream, enc, hbuf, cinit);

    // att1 = enc_h @ W_ea^T + b_ea  (M=12544, N=512) -> f16
    hipLaunchKernelGGL((gemm_k512<EPI_F16B>), dim3(4, 98), dim3(256), 0, stream,
                       enc_h, Wea_h, 512, b_ea, (float*)nullptr, att1_h, (const int*)nullptr);
    // embIH = embg @ WihE_p^T + bsum_p  (M=1280, N=2048 permuted c=4d+g) -> f32
    hipLaunchKernelGGL((gemm_k512<EPI_F32B>), dim3(16, 10), dim3(256), 0, stream,
                       embg, WihE_p, 2048, bsum_p, embIH, (f16*)nullptr, (const int*)nullptr);

    // 20-step recurrence: 16 quads x 16 slices, 3 slot syncs/step
    hipLaunchKernelGGL(k_loopQ, dim3(256), dim3(512), 0, stream,
                       att1_h, enc_h, W1L, BpL, embIH, W_fa, b_fa, bcat,
                       lens, cinit, hbuf, alph_out, xatt2, xvz, gsync);

    // predictions = h(1..20) @ W_fc^T + b_fc, masked scatter (XCD-pinned swizzle)
    hipLaunchKernelGGL((gemm_k512<EPI_PREDS>), dim3(2400), dim3(256), 0, stream,
                       hbuf + 32768, Wfc_h, CVP, b_fc, out, (f16*)nullptr, lens);
}